// Round 1
// baseline (1581.751 us; speedup 1.0000x reference)
//
#include <hip/hip_runtime.h>
#include <cstdint>
#include <cstddef>

#define DD 64
constexpr float BN_EPS  = 1e-5f;
constexpr float DEG_EPS = 1e-6f;

__device__ __forceinline__ float fatomic_add(float* p, float v) {
    return unsafeAtomicAdd(p, v);   // hardware global_atomic_add_f32 (coarse-grained mem)
}

// ---------------- node linears: o = h @ W^T + b, one matrix per blockIdx.y ----
__global__ __launch_bounds__(256) void k_node_linear(
    const float* __restrict__ h, int N,
    const float* __restrict__ w0, const float* __restrict__ b0, float* __restrict__ o0,
    const float* __restrict__ w1, const float* __restrict__ b1, float* __restrict__ o1,
    const float* __restrict__ w2, const float* __restrict__ b2, float* __restrict__ o2,
    const float* __restrict__ w3, const float* __restrict__ b3, float* __restrict__ o3,
    const float* __restrict__ w4, const float* __restrict__ b4, float* __restrict__ o4)
{
    const float* w; const float* b; float* o;
    switch (blockIdx.y) {
        case 0:  w = w0; b = b0; o = o0; break;
        case 1:  w = w1; b = b1; o = o1; break;
        case 2:  w = w2; b = b2; o = o2; break;
        case 3:  w = w3; b = b3; o = o3; break;
        default: w = w4; b = b4; o = o4; break;
    }
    int n = blockIdx.x * 256 + threadIdx.x;
    if (n >= N) return;
    float hr[DD];
    const float4* h4 = reinterpret_cast<const float4*>(h + (size_t)n * DD);
    #pragma unroll
    for (int j = 0; j < 16; ++j) {
        float4 v = h4[j];
        hr[4*j+0] = v.x; hr[4*j+1] = v.y; hr[4*j+2] = v.z; hr[4*j+3] = v.w;
    }
    float4* op = reinterpret_cast<float4*>(o + (size_t)n * DD);
    for (int d4 = 0; d4 < 16; ++d4) {
        float acc[4];
        #pragma unroll
        for (int j = 0; j < 4; ++j) acc[j] = b[d4*4 + j];     // uniform -> s_load
        #pragma unroll
        for (int k4 = 0; k4 < 16; ++k4) {
            #pragma unroll
            for (int j = 0; j < 4; ++j) {
                float4 wv = reinterpret_cast<const float4*>(w + (size_t)(d4*4 + j) * DD)[k4];
                acc[j] += hr[4*k4+0]*wv.x + hr[4*k4+1]*wv.y
                        + hr[4*k4+2]*wv.z + hr[4*k4+3]*wv.w;
            }
        }
        float4 ov = {acc[0], acc[1], acc[2], acc[3]};
        op[d4] = ov;
    }
}

// ---------------- edge gate pre-BN: g = B3e + B1h[src] + B2h[dst] + b3 -------
__global__ __launch_bounds__(256) void k_edge_g(
    const float* __restrict__ e, const int* __restrict__ src, const int* __restrict__ dst,
    const float* __restrict__ B1h, const float* __restrict__ B2h,
    const float* __restrict__ w, const float* __restrict__ b,
    float* __restrict__ g, int E)
{
    int ee = blockIdx.x * 256 + threadIdx.x;
    if (ee >= E) return;
    float er[DD];
    const float4* e4 = reinterpret_cast<const float4*>(e + (size_t)ee * DD);
    #pragma unroll
    for (int j = 0; j < 16; ++j) {
        float4 v = e4[j];
        er[4*j+0] = v.x; er[4*j+1] = v.y; er[4*j+2] = v.z; er[4*j+3] = v.w;
    }
    int s = src[ee], t = dst[ee];
    const float4* p1 = reinterpret_cast<const float4*>(B1h + (size_t)s * DD);
    const float4* p2 = reinterpret_cast<const float4*>(B2h + (size_t)t * DD);
    float4* go = reinterpret_cast<float4*>(g + (size_t)ee * DD);
    for (int d4 = 0; d4 < 16; ++d4) {
        float acc[4];
        #pragma unroll
        for (int j = 0; j < 4; ++j) acc[j] = b[d4*4 + j];
        #pragma unroll
        for (int k4 = 0; k4 < 16; ++k4) {
            #pragma unroll
            for (int j = 0; j < 4; ++j) {
                float4 wv = reinterpret_cast<const float4*>(w + (size_t)(d4*4 + j) * DD)[k4];
                acc[j] += er[4*k4+0]*wv.x + er[4*k4+1]*wv.y
                        + er[4*k4+2]*wv.z + er[4*k4+3]*wv.w;
            }
        }
        float4 g1 = p1[d4], g2 = p2[d4];
        float4 ov = {acc[0] + g1.x + g2.x, acc[1] + g1.y + g2.y,
                     acc[2] + g1.z + g2.z, acc[3] + g1.w + g2.w};
        go[d4] = ov;
    }
}

// ---------------- per-column sum / sumsq over a [rows,64] buffer -------------
__global__ __launch_bounds__(256) void k_col_stats(
    const float* __restrict__ x, long long total, float* __restrict__ sums /*[128]*/)
{
    int tid = threadIdx.x;
    long long idx = (long long)blockIdx.x * 256 + tid;
    long long stride = (long long)gridDim.x * 256;   // %64 == 0 -> d fixed per thread
    float ps = 0.f, pq = 0.f;
    for (; idx < total; idx += stride) {
        float v = x[idx];
        ps += v; pq += v * v;
    }
    __shared__ float red[256];
    red[tid] = ps; __syncthreads();
    if (tid < 64) fatomic_add(&sums[tid],      red[tid] + red[tid+64] + red[tid+128] + red[tid+192]);
    __syncthreads();
    red[tid] = pq; __syncthreads();
    if (tid < 64) fatomic_add(&sums[64 + tid], red[tid] + red[tid+64] + red[tid+128] + red[tid+192]);
}

// ---------------- fold stats into scale/shift --------------------------------
__global__ void k_bn_final(const float* __restrict__ sums, float inv_cnt,
                           const float* __restrict__ gamma, const float* __restrict__ beta,
                           float* __restrict__ scale, float* __restrict__ shift)
{
    int d = threadIdx.x;
    if (d >= DD) return;
    float mean = sums[d] * inv_cnt;
    float var  = fmaxf(sums[64 + d] * inv_cnt - mean * mean, 0.f);
    float rs   = rsqrtf(var + BN_EPS);
    float sc   = gamma[d] * rs;
    scale[d] = sc;
    shift[d] = beta[d] - mean * sc;
}

// ---------------- sigma + segment-sum scatter --------------------------------
__global__ __launch_bounds__(256) void k_edge_scatter(
    const float* __restrict__ g, const float* __restrict__ e,
    const int* __restrict__ src, const int* __restrict__ dst,
    const float* __restrict__ A2h, const float* __restrict__ A3h,
    const float* __restrict__ scale, const float* __restrict__ shift,
    float* __restrict__ num_f, float* __restrict__ den_f,
    float* __restrict__ num_b, float* __restrict__ den_b, int E)
{
    long long idx = (long long)blockIdx.x * 256 + threadIdx.x;
    if (idx >= (long long)E * DD) return;
    int d  = (int)(idx & (DD - 1));
    int ee = (int)(idx >> 6);
    int s = src[ee], t = dst[ee];
    float x = g[idx] * scale[d] + shift[d];
    x = fmaxf(x, 0.f) + e[idx];
    float sig = 1.f / (1.f + __expf(-x));
    float a2 = A2h[(size_t)s * DD + d];
    float a3 = A3h[(size_t)t * DD + d];
    fatomic_add(&num_f[(size_t)t * DD + d], sig * a2);
    fatomic_add(&den_f[(size_t)t * DD + d], sig);
    fatomic_add(&num_b[(size_t)s * DD + d], sig * a3);
    fatomic_add(&den_b[(size_t)s * DD + d], sig);
}

// ---------------- h_pre = A1h + num/den (fwd+bwd), + column stats ------------
__global__ __launch_bounds__(256) void k_node_pre(
    const float* __restrict__ A1h,
    const float* __restrict__ num_f, const float* __restrict__ den_f,
    const float* __restrict__ num_b, const float* __restrict__ den_b,
    float* __restrict__ hpre, float* __restrict__ sums, long long total)
{
    int tid = threadIdx.x;
    long long idx = (long long)blockIdx.x * 256 + tid;
    long long stride = (long long)gridDim.x * 256;
    float ps = 0.f, pq = 0.f;
    for (; idx < total; idx += stride) {
        float v = A1h[idx] + num_f[idx] / (den_f[idx] + DEG_EPS)
                           + num_b[idx] / (den_b[idx] + DEG_EPS);
        hpre[idx] = v;
        ps += v; pq += v * v;
    }
    __shared__ float red[256];
    red[tid] = ps; __syncthreads();
    if (tid < 64) fatomic_add(&sums[tid],      red[tid] + red[tid+64] + red[tid+128] + red[tid+192]);
    __syncthreads();
    red[tid] = pq; __syncthreads();
    if (tid < 64) fatomic_add(&sums[64 + tid], red[tid] + red[tid+64] + red[tid+128] + red[tid+192]);
}

// ---------------- finish h: BN affine + relu + residual (in place) -----------
__global__ __launch_bounds__(256) void k_node_out(
    const float* __restrict__ h,
    const float* __restrict__ scale, const float* __restrict__ shift,
    float* __restrict__ out, long long total)
{
    long long idx = (long long)blockIdx.x * 256 + threadIdx.x;
    long long stride = (long long)gridDim.x * 256;
    for (; idx < total; idx += stride) {
        int d = (int)(idx & (DD - 1));
        float v = out[idx] * scale[d] + shift[d];
        out[idx] = fmaxf(v, 0.f) + h[idx];
    }
}

extern "C" void kernel_launch(void* const* d_in, const int* in_sizes, int n_in,
                              void* d_out, int out_size, void* d_ws, size_t ws_size,
                              hipStream_t stream)
{
    const float* h    = (const float*)d_in[0];
    const float* e    = (const float*)d_in[1];
    const int*   src  = (const int*)d_in[2];
    const int*   dst  = (const int*)d_in[3];
    const float* A1w  = (const float*)d_in[4];
    const float* A1b  = (const float*)d_in[5];
    const float* A2w  = (const float*)d_in[6];
    const float* A2b  = (const float*)d_in[7];
    const float* A3w  = (const float*)d_in[8];
    const float* A3b  = (const float*)d_in[9];
    const float* B1w  = (const float*)d_in[10];
    const float* B1b  = (const float*)d_in[11];
    const float* B2w  = (const float*)d_in[12];
    const float* B2b  = (const float*)d_in[13];
    const float* B3w  = (const float*)d_in[14];
    const float* B3b  = (const float*)d_in[15];
    const float* bnhg = (const float*)d_in[16];
    const float* bnhb = (const float*)d_in[17];
    const float* bneg = (const float*)d_in[18];
    const float* bneb = (const float*)d_in[19];

    const int N = in_sizes[0] / DD;
    const int E = in_sizes[1] / DD;
    const size_t ND = (size_t)N * DD;
    const size_t ED = (size_t)E * DD;

    float* ws    = (float*)d_ws;
    float* A1h   = ws + 0 * ND;
    float* A2h   = ws + 1 * ND;
    float* A3h   = ws + 2 * ND;
    float* B1h   = ws + 3 * ND;
    float* B2h   = ws + 4 * ND;
    float* num_f = ws + 5 * ND;
    float* den_f = ws + 6 * ND;
    float* num_b = ws + 7 * ND;
    float* den_b = ws + 8 * ND;
    float* stats = ws + 9 * ND;   // 512 floats:
    // [0:64] e_sum [64:128] e_sq [128:192] e_scale [192:256] e_shift
    // [256:320] h_sum [320:384] h_sq [384:448] h_scale [448:512] h_shift

    float* out  = (float*)d_out;
    float* gbuf = out + ND;       // e-output region doubles as scratch for pre-BN gate

    // zero the atomic accumulators (num/den + stats) each call
    hipMemsetAsync(num_f, 0, (4 * ND + 512) * sizeof(float), stream);

    dim3 blk(256);
    int nb_n = (N + 255) / 256;
    k_node_linear<<<dim3(nb_n, 5), blk, 0, stream>>>(h, N,
        A1w, A1b, A1h,  A2w, A2b, A2h,  A3w, A3b, A3h,
        B1w, B1b, B1h,  B2w, B2b, B2h);

    int nb_e = (E + 255) / 256;
    k_edge_g<<<nb_e, blk, 0, stream>>>(e, src, dst, B1h, B2h, B3w, B3b, gbuf, E);

    k_col_stats<<<2048, blk, 0, stream>>>(gbuf, (long long)ED, stats);
    k_bn_final<<<1, 64, 0, stream>>>(stats, 1.0f / (float)E, bneg, bneb,
                                     stats + 128, stats + 192);

    int nb_es = (int)((ED + 255) / 256);
    k_edge_scatter<<<nb_es, blk, 0, stream>>>(gbuf, e, src, dst, A2h, A3h,
        stats + 128, stats + 192, num_f, den_f, num_b, den_b, E);

    k_node_pre<<<1024, blk, 0, stream>>>(A1h, num_f, den_f, num_b, den_b,
        out, stats + 256, (long long)ND);
    k_bn_final<<<1, 64, 0, stream>>>(stats + 256, 1.0f / (float)N, bnhg, bnhb,
                                     stats + 384, stats + 448);
    k_node_out<<<1024, blk, 0, stream>>>(h, stats + 384, stats + 448,
                                         out, (long long)ND);

    // finally, output e unchanged (overwrites the gbuf scratch)
    hipMemcpyAsync(gbuf, e, ED * sizeof(float), hipMemcpyDeviceToDevice, stream);
}